// Round 2
// baseline (322.129 us; speedup 1.0000x reference)
//
#include <hip/hip_runtime.h>
#include <hip/hip_bf16.h>

typedef __bf16 bf16;
typedef __bf16 bf16x4 __attribute__((ext_vector_type(4)));
typedef __bf16 bf16x8 __attribute__((ext_vector_type(8)));
typedef float floatx4 __attribute__((ext_vector_type(4)));

#define MFMA16(a, b, c) __builtin_amdgcn_mfma_f32_16x16x32_bf16((a), (b), (c), 0, 0, 0)

constexpr int NHEADS = 16;

// async global->LDS, 16B per lane; LDS dest = wave-uniform base + lane*16
__device__ __forceinline__ void gld16(const bf16* g, bf16* l) {
  __builtin_amdgcn_global_load_lds(
      (const __attribute__((address_space(1))) void*)g,
      (__attribute__((address_space(3))) void*)l, 16, 0, 0);
}

// ---------------------------------------------------------------------------
// fp32 -> bf16 convert, 8 elems/thread, exact grids (n % 2048 == 0)
// ---------------------------------------------------------------------------
__global__ __launch_bounds__(256) void cvt_bf16(const float* __restrict__ src,
                                                bf16* __restrict__ dst) {
  const int i = blockIdx.x * 256 + threadIdx.x;
  floatx4 a = ((const floatx4*)src)[2 * i];
  floatx4 b = ((const floatx4*)src)[2 * i + 1];
  bf16x8 o = {(bf16)a[0], (bf16)a[1], (bf16)a[2], (bf16)a[3],
              (bf16)b[0], (bf16)b[1], (bf16)b[2], (bf16)b[3]};
  ((bf16x8*)dst)[i] = o;
}

// ---------------------------------------------------------------------------
// GEMM (m97 structure): C[m][n] = sum_k A[m][k]*W[n][k] + bias[n]
// (UNCHANGED.) global_load_lds(16B), BK=32, 128x128 tile.
// MODE 0: scatter -> q[B,H,T,64], k[B,H,T,64], vT[B,H,64,T] (bf16)
// MODE 1: plain fp32 store outf[m][n]
// ---------------------------------------------------------------------------
template <int MODE>
__global__ __launch_bounds__(256) void gemm_bt(
    const bf16* __restrict__ A, const bf16* __restrict__ W,
    const float* __restrict__ bias, bf16* __restrict__ out0,
    bf16* __restrict__ out1, bf16* __restrict__ out2,
    float* __restrict__ outf) {
  __shared__ __attribute__((aligned(16))) bf16 lds_a[128 * 32];
  __shared__ __attribute__((aligned(16))) bf16 lds_b[128 * 32];

  const int tid = threadIdx.x;
  const int wid = tid >> 6;
  const int lane = tid & 63;
  const int quad = lane >> 4;
  const int l16 = lane & 15;
  const int block_m = blockIdx.y * 128;
  const int block_n = blockIdx.x * 128;
  const int wm = (wid >> 1) * 64;
  const int wn = (wid & 1) * 64;

  floatx4 acc[4][4];
#pragma unroll
  for (int i = 0; i < 4; ++i)
#pragma unroll
    for (int j = 0; j < 4; ++j) acc[i][j] = (floatx4){0.f, 0.f, 0.f, 0.f};

  for (int k0 = 0; k0 < 1024; k0 += 32) {
    // stage A,W tiles: 512 x 16B slots; slot s -> row = s>>2, blk = s&3.
#pragma unroll
    for (int i = 0; i < 2; ++i) {
      const int slot = wid * 128 + i * 64 + lane;
      const int row = slot >> 2;
      const int blk = slot & 3;
      const int lbase = (wid * 128 + i * 64) * 8;  // elems, wave-uniform
      gld16(&A[(size_t)(block_m + row) * 1024 + k0 + blk * 8], &lds_a[lbase]);
      gld16(&W[(size_t)(block_n + row) * 1024 + k0 + blk * 8], &lds_b[lbase]);
    }
    __syncthreads();

    bf16x8 af[4], bf_[4];
#pragma unroll
    for (int mt = 0; mt < 4; ++mt)
      af[mt] = *(const bf16x8*)&lds_a[(wm + mt * 16 + l16) * 32 + quad * 8];
#pragma unroll
    for (int nt = 0; nt < 4; ++nt)
      bf_[nt] = *(const bf16x8*)&lds_b[(wn + nt * 16 + l16) * 32 + quad * 8];
#pragma unroll
    for (int mt = 0; mt < 4; ++mt)
#pragma unroll
      for (int nt = 0; nt < 4; ++nt)
        acc[mt][nt] = MFMA16(af[mt], bf_[nt], acc[mt][nt]);
    __syncthreads();
  }

  // Epilogue. C/D layout (16x16x32): col n = lane&15, row m = quad*4 + reg.
#pragma unroll
  for (int nt = 0; nt < 4; ++nt) {
    const int n = block_n + wn + nt * 16 + l16;
    const float bv = bias[n];
#pragma unroll
    for (int mt = 0; mt < 4; ++mt) {
#pragma unroll
      for (int r = 0; r < 4; ++r) {
        const int m = block_m + wm + mt * 16 + quad * 4 + r;
        const float v = acc[mt][nt][r] + bv;
        if constexpr (MODE == 1) {
          outf[(size_t)m * 1024 + n] = v;  // fp32 final output
        } else {
          const int which = n >> 10;  // 0=q 1=k 2=v
          const int d = n & 1023;
          const int h = d >> 6;
          const int dd = d & 63;
          const int b = m >> 11;  // m = b*2048 + t
          const int t = m & 2047;
          const size_t bh = (size_t)(b * NHEADS + h);
          if (which == 0)
            out0[(bh * 2048 + t) * 64 + dd] = (bf16)v;
          else if (which == 1)
            out1[(bh * 2048 + t) * 64 + dd] = (bf16)v;
          else
            out2[(bh * 64 + dd) * 2048 + t] = (bf16)v;  // v transposed
        }
      }
    }
  }
}

// ---------------------------------------------------------------------------
// Flash attention v6: 1D grid 1024, XCD-swizzled decode (each XCD owns 8
// contiguous (b,h) pairs = 4MB K/V -> L2-resident, K/V fetched ~once/XCD).
// K/V TRIPLE-buffered in LDS via global_load_lds; stage(t+2) issued each
// tile; counted s_waitcnt vmcnt(8) (never 0 in-loop) + raw s_barrier --
// staging latency gets ~2 tiles of compute to hide under (T3+T4).
// Source addrs XOR-pre-swizzled (16B slot c ^= row&7), LDS dest linear,
// same XOR on ds_read_b128 side -> conflict-free fragment reads.
// Fixed-offset exp2, rowsum via MFMA ones-fragment. P round trip in LDS.
// q,k: [B,H,T,64] bf16; vt: [B,H,64,T] bf16; ctx out: [B,T,1024] bf16.
// ---------------------------------------------------------------------------
__global__ __launch_bounds__(256) void flash_attn(
    const bf16* __restrict__ q, const bf16* __restrict__ k,
    const bf16* __restrict__ vt, bf16* __restrict__ ctx) {
  __shared__ __attribute__((aligned(16))) bf16 k_lds[3][64 * 64];
  __shared__ __attribute__((aligned(16))) bf16 v_lds[3][64 * 64];
  __shared__ __attribute__((aligned(16))) bf16 p_lds[4][32][72];

  const int tid = threadIdx.x;
  const int wid = tid >> 6;
  const int lane = tid & 63;
  const int quad = lane >> 4;
  const int l16 = lane & 15;

  // XCD-aware decode: dispatch round-robins wg%8 across XCDs; give each XCD
  // a contiguous chunk of (qtile,h,b) space so one XCD sees all 16 q-tiles
  // of its 8 (b,h) pairs (K/V working set = 8 * 512KB = 4MB = L2/XCD).
  const int wg = blockIdx.x;
  const int nl = (wg & 7) * 128 + (wg >> 3);  // bijective, 1024 % 8 == 0
  const int q0 = (nl & 15) * 128;
  const int h = (nl >> 4) & 15;
  const int b = nl >> 8;
  const size_t bh = (size_t)(b * NHEADS + h);
  const bf16* qb = q + bh * 2048 * 64;
  const bf16* kb = k + bh * 2048 * 64;
  const bf16* vb = vt + bh * 64 * 2048;

  const bf16x8 ones = {(bf16)1.f, (bf16)1.f, (bf16)1.f, (bf16)1.f,
                       (bf16)1.f, (bf16)1.f, (bf16)1.f, (bf16)1.f};

  // ---- staging geometry: wave handles 16 rows of K tile and 16 of V tile.
  // slot s (16B) -> row = s>>3, col16 = s&7; source col pre-swizzled by
  // col16 ^ (row&7); LDS dest linear (wave-uniform base + lane*16).
  const int slot0 = wid * 128 + lane;      // call 0
  const int slot1 = slot0 + 64;            // call 1
  const int row0 = slot0 >> 3, c0 = (slot0 & 7) ^ (row0 & 7);
  const int row1 = slot1 >> 3, c1 = (slot1 & 7) ^ (row1 & 7);
  const bf16* kst0 = kb + (size_t)row0 * 64 + c0 * 8;   // + kt*64 per tile
  const bf16* kst1 = kb + (size_t)row1 * 64 + c1 * 8;
  const bf16* vst0 = vb + (size_t)row0 * 2048 + c0 * 8; // + kt per tile
  const bf16* vst1 = vb + (size_t)row1 * 2048 + c1 * 8;
  const int ldst0 = wid * 1024;            // elems, wave-uniform
  const int ldst1 = wid * 1024 + 512;

  // ---- fragment-read geometry (swizzled): row = X*16 + l16,
  // elem = row*64 + ((slotc ^ (row&7)) * 8), slotc = quad (lo) / quad+4 (hi)
  const int r7 = l16 & 7;
  const int ro = l16 * 64;
  const int sw0 = ro + ((quad ^ r7) * 8);
  const int sw1 = ro + (((quad + 4) ^ r7) * 8);

  bf16x8 qa[2][2];
#pragma unroll
  for (int s = 0; s < 2; ++s) {
    const int row = q0 + wid * 32 + s * 16 + l16;
    qa[s][0] = *(const bf16x8*)&qb[(size_t)row * 64 + quad * 8];
    qa[s][1] = *(const bf16x8*)&qb[(size_t)row * 64 + 32 + quad * 8];
  }

  floatx4 oacc[2][4];
  floatx4 lacc[2];
#pragma unroll
  for (int s = 0; s < 2; ++s) {
    lacc[s] = (floatx4){0.f, 0.f, 0.f, 0.f};
#pragma unroll
    for (int dt = 0; dt < 4; ++dt) oacc[s][dt] = (floatx4){0.f, 0.f, 0.f, 0.f};
  }

  // ---- prologue: stage tiles 0 and 1 into buffers 0 and 1 (8 loads out)
  gld16(kst0, &k_lds[0][ldst0]);
  gld16(kst1, &k_lds[0][ldst1]);
  gld16(vst0, &v_lds[0][ldst0]);
  gld16(vst1, &v_lds[0][ldst1]);
  gld16(kst0 + (size_t)64 * 64, &k_lds[1][ldst0]);
  gld16(kst1 + (size_t)64 * 64, &k_lds[1][ldst1]);
  gld16(vst0 + 64, &v_lds[1][ldst0]);
  gld16(vst1 + 64, &v_lds[1][ldst1]);

  constexpr float L2E = 1.4426950408889634f;
  for (int t = 0; t < 32; ++t) {
    const int kt = t * 64;
    const int cur = t % 3;
    // ---- issue stage(t+2) into buffer (t+2)%3 (guarded by prev trailing
    // barrier: that buffer's readers are done). 2 tiles stay in flight.
    if (t + 2 < 32) {
      const int nb = (t + 2) % 3;
      const size_t ko = (size_t)(kt + 128) * 64;
      gld16(kst0 + ko, &k_lds[nb][ldst0]);
      gld16(kst1 + ko, &k_lds[nb][ldst1]);
      gld16(vst0 + (kt + 128), &v_lds[nb][ldst0]);
      gld16(vst1 + (kt + 128), &v_lds[nb][ldst1]);
    }

    // ---- counted wait: stage(t) done, stage(t+1)/(t+2) stay outstanding.
    if (t < 30) {
      asm volatile("s_waitcnt vmcnt(8)" ::: "memory");
    } else if (t == 30) {
      asm volatile("s_waitcnt vmcnt(4)" ::: "memory");
    } else {
      asm volatile("s_waitcnt vmcnt(0)" ::: "memory");
    }
    __builtin_amdgcn_sched_barrier(0);
    __builtin_amdgcn_s_barrier();  // all waves' stage(t) complete
    __builtin_amdgcn_sched_barrier(0);

    // ---- K and V fragments for this tile (conflict-free swizzled reads)
    const bf16* kbuf = &k_lds[cur][0];
    const bf16* vbuf = &v_lds[cur][0];
    bf16x8 kf0[4], kf1[4], vf0[4], vf1[4];
#pragma unroll
    for (int nt = 0; nt < 4; ++nt) {
      kf0[nt] = *(const bf16x8*)&kbuf[nt * 1024 + sw0];
      kf1[nt] = *(const bf16x8*)&kbuf[nt * 1024 + sw1];
    }
#pragma unroll
    for (int dt = 0; dt < 4; ++dt) {
      vf0[dt] = *(const bf16x8*)&vbuf[dt * 1024 + sw0];
      vf1[dt] = *(const bf16x8*)&vbuf[dt * 1024 + sw1];
    }

    // ---- S = QK^T, P = exp2(S*log2e/8 - 3*log2e) -> LDS (C layout)
#pragma unroll
    for (int s = 0; s < 2; ++s) {
      floatx4 st[4];
#pragma unroll
      for (int nt = 0; nt < 4; ++nt) {
        floatx4 a0 = (floatx4){0.f, 0.f, 0.f, 0.f};
        a0 = MFMA16(qa[s][0], kf0[nt], a0);
        st[nt] = MFMA16(qa[s][1], kf1[nt], a0);
      }
#pragma unroll
      for (int nt = 0; nt < 4; ++nt)
#pragma unroll
        for (int r = 0; r < 4; ++r) {
          const float p =
              __builtin_amdgcn_exp2f(fmaf(st[nt][r], 0.125f * L2E, -3.0f * L2E));
          p_lds[wid][s * 16 + quad * 4 + r][nt * 16 + l16] = (bf16)p;
        }
    }

    // ---- O += P V ; l += P @ 1 (rowsum via matrix pipe)
#pragma unroll
    for (int s = 0; s < 2; ++s) {
      bf16x8 pa0 = *(const bf16x8*)&p_lds[wid][s * 16 + l16][quad * 8];
      bf16x8 pa1 = *(const bf16x8*)&p_lds[wid][s * 16 + l16][32 + quad * 8];
#pragma unroll
      for (int dt = 0; dt < 4; ++dt) {
        oacc[s][dt] = MFMA16(pa0, vf0[dt], oacc[s][dt]);
        oacc[s][dt] = MFMA16(pa1, vf1[dt], oacc[s][dt]);
      }
      lacc[s] = MFMA16(pa0, ones, lacc[s]);
      lacc[s] = MFMA16(pa1, ones, lacc[s]);
    }

    // ---- all my LDS reads done, then block-wide fence before anyone
    // overwrites buffer cur ( = (t+3)%3 ) next iteration.
    asm volatile("s_waitcnt lgkmcnt(0)" ::: "memory");
    __builtin_amdgcn_sched_barrier(0);
    __builtin_amdgcn_s_barrier();
    __builtin_amdgcn_sched_barrier(0);
  }

  // ---- write ctx[b, t, h*64 + d] = O / l  (lacc col-uniform: own lane ok)
#pragma unroll
  for (int s = 0; s < 2; ++s) {
    float linv[4];
#pragma unroll
    for (int r = 0; r < 4; ++r) linv[r] = 1.f / lacc[s][r];
    const size_t base =
        ((size_t)b * 2048 + q0 + wid * 32 + s * 16) * 1024 + h * 64;
#pragma unroll
    for (int dt = 0; dt < 4; ++dt)
#pragma unroll
      for (int r = 0; r < 4; ++r) {
        const float v = oacc[s][dt][r] * linv[r];
        ctx[base + (size_t)(quad * 4 + r) * 1024 + dt * 16 + l16] = (bf16)v;
      }
  }
}

// ---------------------------------------------------------------------------
extern "C" void kernel_launch(void* const* d_in, const int* in_sizes, int n_in,
                              void* d_out, int out_size, void* d_ws,
                              size_t ws_size, hipStream_t stream) {
  const float* x = (const float*)d_in[0];       // [4,2048,1024] fp32
  const float* qkv_w = (const float*)d_in[1];   // [3072,1024]  fp32
  const float* qkv_b = (const float*)d_in[2];   // [3072]       fp32
  const float* out_w = (const float*)d_in[3];   // [1024,1024]  fp32
  const float* out_b = (const float*)d_in[4];   // [1024]       fp32
  float* out = (float*)d_out;                   // [4,2048,1024] fp32

  // xb (16.8MB) lives in d_out's 33.6MB: read only before the final GEMM
  bf16* xb = (bf16*)d_out;

  bf16* ws = (bf16*)d_ws;
  const size_t SZ = (size_t)8192 * 1024;
  bf16* qkvwb = ws;                       // [3072,1024]
  bf16* outwb = qkvwb + 3072 * 1024;      // [1024,1024]
  bf16* qws = outwb + 1024 * 1024;        // [B,H,T,64]
  bf16* kws = qws + SZ;                   // [B,H,T,64]
  bf16* vtws = kws + SZ;                  // [B,H,64,T]
  bf16* ctx = vtws + SZ;                  // [B,T,1024]

  cvt_bf16<<<4096, 256, 0, stream>>>(x, xb);
  cvt_bf16<<<1536, 256, 0, stream>>>(qkv_w, qkvwb);
  cvt_bf16<<<512, 256, 0, stream>>>(out_w, outwb);

  gemm_bt<0><<<dim3(24, 64), 256, 0, stream>>>(xb, qkvwb, qkv_b, qws, kws,
                                               vtws, nullptr);
  flash_attn<<<1024, 256, 0, stream>>>(qws, kws, vtws, ctx);
  gemm_bt<1><<<dim3(8, 64), 256, 0, stream>>>(ctx, outwb, out_b, nullptr,
                                              nullptr, nullptr, out);
}

// Round 3
// 307.557 us; speedup vs baseline: 1.0474x; 1.0474x over previous
//
#include <hip/hip_runtime.h>
#include <hip/hip_bf16.h>

typedef __bf16 bf16;
typedef __bf16 bf16x4 __attribute__((ext_vector_type(4)));
typedef __bf16 bf16x8 __attribute__((ext_vector_type(8)));
typedef float floatx4 __attribute__((ext_vector_type(4)));

#define MFMA16(a, b, c) __builtin_amdgcn_mfma_f32_16x16x32_bf16((a), (b), (c), 0, 0, 0)

constexpr int NHEADS = 16;

// async global->LDS, 16B per lane; LDS dest = wave-uniform base + lane*16
__device__ __forceinline__ void gld16(const bf16* g, bf16* l) {
  __builtin_amdgcn_global_load_lds(
      (const __attribute__((address_space(1))) void*)g,
      (__attribute__((address_space(3))) void*)l, 16, 0, 0);
}

// ---------------------------------------------------------------------------
// fp32 -> bf16 convert, 8 elems/thread, exact grids (n % 2048 == 0)
// ---------------------------------------------------------------------------
__global__ __launch_bounds__(256) void cvt_bf16(const float* __restrict__ src,
                                                bf16* __restrict__ dst) {
  const int i = blockIdx.x * 256 + threadIdx.x;
  floatx4 a = ((const floatx4*)src)[2 * i];
  floatx4 b = ((const floatx4*)src)[2 * i + 1];
  bf16x8 o = {(bf16)a[0], (bf16)a[1], (bf16)a[2], (bf16)a[3],
              (bf16)b[0], (bf16)b[1], (bf16)b[2], (bf16)b[3]};
  ((bf16x8*)dst)[i] = o;
}

// ---------------------------------------------------------------------------
// GEMM (m97 structure): C[m][n] = sum_k A[m][k]*W[n][k] + bias[n]
// global_load_lds(16B), BK=32, 128x128 tile.
// MODE 0: scatter -> q[B,H,T,64], k[B,H,T,64], vT[B,H,64,T] (bf16)
//         (V path packs 4 consecutive t into one bf16x4 store)
// MODE 1: plain fp32 store outf[m][n]
// ---------------------------------------------------------------------------
template <int MODE>
__global__ __launch_bounds__(256) void gemm_bt(
    const bf16* __restrict__ A, const bf16* __restrict__ W,
    const float* __restrict__ bias, bf16* __restrict__ out0,
    bf16* __restrict__ out1, bf16* __restrict__ out2,
    float* __restrict__ outf) {
  __shared__ __attribute__((aligned(16))) bf16 lds_a[128 * 32];
  __shared__ __attribute__((aligned(16))) bf16 lds_b[128 * 32];

  const int tid = threadIdx.x;
  const int wid = tid >> 6;
  const int lane = tid & 63;
  const int quad = lane >> 4;
  const int l16 = lane & 15;
  const int block_m = blockIdx.y * 128;
  const int block_n = blockIdx.x * 128;
  const int wm = (wid >> 1) * 64;
  const int wn = (wid & 1) * 64;

  floatx4 acc[4][4];
#pragma unroll
  for (int i = 0; i < 4; ++i)
#pragma unroll
    for (int j = 0; j < 4; ++j) acc[i][j] = (floatx4){0.f, 0.f, 0.f, 0.f};

  for (int k0 = 0; k0 < 1024; k0 += 32) {
    // stage A,W tiles: 512 x 16B slots; slot s -> row = s>>2, blk = s&3.
#pragma unroll
    for (int i = 0; i < 2; ++i) {
      const int slot = wid * 128 + i * 64 + lane;
      const int row = slot >> 2;
      const int blk = slot & 3;
      const int lbase = (wid * 128 + i * 64) * 8;  // elems, wave-uniform
      gld16(&A[(size_t)(block_m + row) * 1024 + k0 + blk * 8], &lds_a[lbase]);
      gld16(&W[(size_t)(block_n + row) * 1024 + k0 + blk * 8], &lds_b[lbase]);
    }
    __syncthreads();

    bf16x8 af[4], bf_[4];
#pragma unroll
    for (int mt = 0; mt < 4; ++mt)
      af[mt] = *(const bf16x8*)&lds_a[(wm + mt * 16 + l16) * 32 + quad * 8];
#pragma unroll
    for (int nt = 0; nt < 4; ++nt)
      bf_[nt] = *(const bf16x8*)&lds_b[(wn + nt * 16 + l16) * 32 + quad * 8];
#pragma unroll
    for (int mt = 0; mt < 4; ++mt)
#pragma unroll
      for (int nt = 0; nt < 4; ++nt)
        acc[mt][nt] = MFMA16(af[mt], bf_[nt], acc[mt][nt]);
    __syncthreads();
  }

  // Epilogue. C/D layout (16x16x32): col n = lane&15, row m = quad*4 + reg.
#pragma unroll
  for (int nt = 0; nt < 4; ++nt) {
    const int n = block_n + wn + nt * 16 + l16;
    const float bv = bias[n];
#pragma unroll
    for (int mt = 0; mt < 4; ++mt) {
      const int m0 = block_m + wm + mt * 16 + quad * 4;  // m = m0 + r
      float v4[4];
#pragma unroll
      for (int r = 0; r < 4; ++r) v4[r] = acc[mt][nt][r] + bv;
      if constexpr (MODE == 1) {
#pragma unroll
        for (int r = 0; r < 4; ++r) outf[(size_t)(m0 + r) * 1024 + n] = v4[r];
      } else {
        const int which = n >> 10;  // 0=q 1=k 2=v (block-uniform)
        const int d = n & 1023;
        const int h = d >> 6;
        const int dd = d & 63;
        const int b = m0 >> 11;  // m = b*2048 + t, t0 % 4 == 0
        const int t0 = m0 & 2047;
        const size_t bh = (size_t)(b * NHEADS + h);
        if (which == 0) {
#pragma unroll
          for (int r = 0; r < 4; ++r)
            out0[(bh * 2048 + t0 + r) * 64 + dd] = (bf16)v4[r];
        } else if (which == 1) {
#pragma unroll
          for (int r = 0; r < 4; ++r)
            out1[(bh * 2048 + t0 + r) * 64 + dd] = (bf16)v4[r];
        } else {
          // v transposed: t = t0 + r consecutive -> one 8B store
          bf16x4 pv = {(bf16)v4[0], (bf16)v4[1], (bf16)v4[2], (bf16)v4[3]};
          *(bf16x4*)&out2[(bh * 64 + dd) * 2048 + t0] = pv;
        }
      }
    }
  }
}

// ---------------------------------------------------------------------------
// Flash attention v7: 1D grid 1024, XCD-swizzled decode (each XCD owns 8
// contiguous (b,h) pairs = 4MB K/V -> L2-resident; FETCH 139->24.6MB).
// K/V DOUBLE-buffered (50KB LDS -> 3 blocks/CU) via global_load_lds;
// stage(t+1) issued before compute(t); counted s_waitcnt vmcnt(4) keeps the
// next tile in flight across both barriers (never drained in-loop).
// Source addrs XOR-pre-swizzled (16B slot c ^= row&7), LDS dest linear,
// same XOR on ds_read_b128 side -> conflict-free fragment reads.
// Fixed-offset exp2, rowsum via MFMA ones-fragment. P round trip in LDS.
// q,k: [B,H,T,64] bf16; vt: [B,H,64,T] bf16; ctx out: [B,T,1024] bf16.
// ---------------------------------------------------------------------------
__global__ __launch_bounds__(256) void flash_attn(
    const bf16* __restrict__ q, const bf16* __restrict__ k,
    const bf16* __restrict__ vt, bf16* __restrict__ ctx) {
  __shared__ __attribute__((aligned(16))) bf16 k_lds[2][64 * 64];
  __shared__ __attribute__((aligned(16))) bf16 v_lds[2][64 * 64];
  __shared__ __attribute__((aligned(16))) bf16 p_lds[4][32][72];

  const int tid = threadIdx.x;
  const int wid = tid >> 6;
  const int lane = tid & 63;
  const int quad = lane >> 4;
  const int l16 = lane & 15;

  // XCD-aware decode: dispatch round-robins wg%8 across XCDs; give each XCD
  // a contiguous chunk of (qtile,h,b) space so one XCD sees all 16 q-tiles
  // of its 8 (b,h) pairs (K/V working set = 8 * 512KB = 4MB = L2/XCD).
  const int wg = blockIdx.x;
  const int nl = (wg & 7) * 128 + (wg >> 3);  // bijective, 1024 % 8 == 0
  const int q0 = (nl & 15) * 128;
  const int h = (nl >> 4) & 15;
  const int b = nl >> 8;
  const size_t bh = (size_t)(b * NHEADS + h);
  const bf16* qb = q + bh * 2048 * 64;
  const bf16* kb = k + bh * 2048 * 64;
  const bf16* vb = vt + bh * 64 * 2048;

  const bf16x8 ones = {(bf16)1.f, (bf16)1.f, (bf16)1.f, (bf16)1.f,
                       (bf16)1.f, (bf16)1.f, (bf16)1.f, (bf16)1.f};

  // ---- staging geometry: wave handles 16 rows of K tile and 16 of V tile.
  // slot s (16B) -> row = s>>3, col16 = s&7; source col pre-swizzled by
  // col16 ^ (row&7); LDS dest linear (wave-uniform base + lane*16).
  const int slot0 = wid * 128 + lane;      // call 0
  const int slot1 = slot0 + 64;            // call 1
  const int row0 = slot0 >> 3, c0 = (slot0 & 7) ^ (row0 & 7);
  const int row1 = slot1 >> 3, c1 = (slot1 & 7) ^ (row1 & 7);
  const bf16* kst0 = kb + (size_t)row0 * 64 + c0 * 8;   // + kt*64 per tile
  const bf16* kst1 = kb + (size_t)row1 * 64 + c1 * 8;
  const bf16* vst0 = vb + (size_t)row0 * 2048 + c0 * 8; // + kt per tile
  const bf16* vst1 = vb + (size_t)row1 * 2048 + c1 * 8;
  const int ldst0 = wid * 1024;            // elems, wave-uniform
  const int ldst1 = wid * 1024 + 512;

  // ---- fragment-read geometry (swizzled): row = X*16 + l16,
  // elem = row*64 + ((slotc ^ (row&7)) * 8), slotc = quad (lo) / quad+4 (hi)
  const int r7 = l16 & 7;
  const int ro = l16 * 64;
  const int sw0 = ro + ((quad ^ r7) * 8);
  const int sw1 = ro + (((quad + 4) ^ r7) * 8);

  bf16x8 qa[2][2];
#pragma unroll
  for (int s = 0; s < 2; ++s) {
    const int row = q0 + wid * 32 + s * 16 + l16;
    qa[s][0] = *(const bf16x8*)&qb[(size_t)row * 64 + quad * 8];
    qa[s][1] = *(const bf16x8*)&qb[(size_t)row * 64 + 32 + quad * 8];
  }

  floatx4 oacc[2][4];
  floatx4 lacc[2];
#pragma unroll
  for (int s = 0; s < 2; ++s) {
    lacc[s] = (floatx4){0.f, 0.f, 0.f, 0.f};
#pragma unroll
    for (int dt = 0; dt < 4; ++dt) oacc[s][dt] = (floatx4){0.f, 0.f, 0.f, 0.f};
  }

  // ---- prologue: stage tile 0 into buffer 0 (4 loads in flight)
  gld16(kst0, &k_lds[0][ldst0]);
  gld16(kst1, &k_lds[0][ldst1]);
  gld16(vst0, &v_lds[0][ldst0]);
  gld16(vst1, &v_lds[0][ldst1]);

  constexpr float L2E = 1.4426950408889634f;
  for (int t = 0; t < 32; ++t) {
    const int kt = t * 64;
    const int cur = t & 1;
    // ---- issue stage(t+1) into the other buffer (its readers from
    // iteration t-1 were drained before the trailing barrier of t-1).
    if (t + 1 < 32) {
      const int nb = cur ^ 1;
      const size_t ko = (size_t)(kt + 64) * 64;
      gld16(kst0 + ko, &k_lds[nb][ldst0]);
      gld16(kst1 + ko, &k_lds[nb][ldst1]);
      gld16(vst0 + (kt + 64), &v_lds[nb][ldst0]);
      gld16(vst1 + (kt + 64), &v_lds[nb][ldst1]);
    }

    // ---- counted wait: stage(t) done per-wave; stage(t+1) stays in flight.
    if (t < 31) {
      asm volatile("s_waitcnt vmcnt(4)" ::: "memory");
    } else {
      asm volatile("s_waitcnt vmcnt(0)" ::: "memory");
    }
    __builtin_amdgcn_sched_barrier(0);
    __builtin_amdgcn_s_barrier();  // block-wide: stage(t) complete
    __builtin_amdgcn_sched_barrier(0);

    // ---- K and V fragments for this tile (conflict-free swizzled reads)
    const bf16* kbuf = &k_lds[cur][0];
    const bf16* vbuf = &v_lds[cur][0];
    bf16x8 kf0[4], kf1[4], vf0[4], vf1[4];
#pragma unroll
    for (int nt = 0; nt < 4; ++nt) {
      kf0[nt] = *(const bf16x8*)&kbuf[nt * 1024 + sw0];
      kf1[nt] = *(const bf16x8*)&kbuf[nt * 1024 + sw1];
    }
#pragma unroll
    for (int dt = 0; dt < 4; ++dt) {
      vf0[dt] = *(const bf16x8*)&vbuf[dt * 1024 + sw0];
      vf1[dt] = *(const bf16x8*)&vbuf[dt * 1024 + sw1];
    }

    // ---- S = QK^T, P = exp2(S*log2e/8 - 3*log2e) -> LDS (C layout)
#pragma unroll
    for (int s = 0; s < 2; ++s) {
      floatx4 st[4];
#pragma unroll
      for (int nt = 0; nt < 4; ++nt) {
        floatx4 a0 = (floatx4){0.f, 0.f, 0.f, 0.f};
        a0 = MFMA16(qa[s][0], kf0[nt], a0);
        st[nt] = MFMA16(qa[s][1], kf1[nt], a0);
      }
#pragma unroll
      for (int nt = 0; nt < 4; ++nt)
#pragma unroll
        for (int r = 0; r < 4; ++r) {
          const float p =
              __builtin_amdgcn_exp2f(fmaf(st[nt][r], 0.125f * L2E, -3.0f * L2E));
          p_lds[wid][s * 16 + quad * 4 + r][nt * 16 + l16] = (bf16)p;
        }
    }

    // ---- O += P V ; l += P @ 1 (rowsum via matrix pipe)
#pragma unroll
    for (int s = 0; s < 2; ++s) {
      bf16x8 pa0 = *(const bf16x8*)&p_lds[wid][s * 16 + l16][quad * 8];
      bf16x8 pa1 = *(const bf16x8*)&p_lds[wid][s * 16 + l16][32 + quad * 8];
#pragma unroll
      for (int dt = 0; dt < 4; ++dt) {
        oacc[s][dt] = MFMA16(pa0, vf0[dt], oacc[s][dt]);
        oacc[s][dt] = MFMA16(pa1, vf1[dt], oacc[s][dt]);
      }
      lacc[s] = MFMA16(pa0, ones, lacc[s]);
      lacc[s] = MFMA16(pa1, ones, lacc[s]);
    }

    // ---- all my LDS reads done, then block-wide fence before anyone
    // overwrites buffer cur^1 next iteration (its stage(t+2) writes).
    asm volatile("s_waitcnt lgkmcnt(0)" ::: "memory");
    __builtin_amdgcn_sched_barrier(0);
    __builtin_amdgcn_s_barrier();
    __builtin_amdgcn_sched_barrier(0);
  }

  // ---- write ctx[b, t, h*64 + d] = O / l  (lacc col-uniform: own lane ok)
#pragma unroll
  for (int s = 0; s < 2; ++s) {
    float linv[4];
#pragma unroll
    for (int r = 0; r < 4; ++r) linv[r] = 1.f / lacc[s][r];
    const size_t base =
        ((size_t)b * 2048 + q0 + wid * 32 + s * 16) * 1024 + h * 64;
#pragma unroll
    for (int dt = 0; dt < 4; ++dt)
#pragma unroll
      for (int r = 0; r < 4; ++r) {
        const float v = oacc[s][dt][r] * linv[r];
        ctx[base + (size_t)(quad * 4 + r) * 1024 + dt * 16 + l16] = (bf16)v;
      }
  }
}

// ---------------------------------------------------------------------------
extern "C" void kernel_launch(void* const* d_in, const int* in_sizes, int n_in,
                              void* d_out, int out_size, void* d_ws,
                              size_t ws_size, hipStream_t stream) {
  const float* x = (const float*)d_in[0];       // [4,2048,1024] fp32
  const float* qkv_w = (const float*)d_in[1];   // [3072,1024]  fp32
  const float* qkv_b = (const float*)d_in[2];   // [3072]       fp32
  const float* out_w = (const float*)d_in[3];   // [1024,1024]  fp32
  const float* out_b = (const float*)d_in[4];   // [1024]       fp32
  float* out = (float*)d_out;                   // [4,2048,1024] fp32

  // xb (16.8MB) lives in d_out's 33.6MB: read only before the final GEMM
  bf16* xb = (bf16*)d_out;

  bf16* ws = (bf16*)d_ws;
  const size_t SZ = (size_t)8192 * 1024;
  bf16* qkvwb = ws;                       // [3072,1024]
  bf16* outwb = qkvwb + 3072 * 1024;      // [1024,1024]
  bf16* qws = outwb + 1024 * 1024;        // [B,H,T,64]
  bf16* kws = qws + SZ;                   // [B,H,T,64]
  bf16* vtws = kws + SZ;                  // [B,H,64,T]
  bf16* ctx = vtws + SZ;                  // [B,T,1024]

  cvt_bf16<<<4096, 256, 0, stream>>>(x, xb);
  cvt_bf16<<<1536, 256, 0, stream>>>(qkv_w, qkvwb);
  cvt_bf16<<<512, 256, 0, stream>>>(out_w, outwb);

  gemm_bt<0><<<dim3(24, 64), 256, 0, stream>>>(xb, qkvwb, qkv_b, qws, kws,
                                               vtws, nullptr);
  flash_attn<<<1024, 256, 0, stream>>>(qws, kws, vtws, ctx);
  gemm_bt<1><<<dim3(8, 64), 256, 0, stream>>>(ctx, outwb, out_b, nullptr,
                                              nullptr, nullptr, out);
}

// Round 4
// 300.527 us; speedup vs baseline: 1.0719x; 1.0234x over previous
//
#include <hip/hip_runtime.h>
#include <hip/hip_bf16.h>

typedef __bf16 bf16;
typedef __bf16 bf16x4 __attribute__((ext_vector_type(4)));
typedef __bf16 bf16x8 __attribute__((ext_vector_type(8)));
typedef float floatx4 __attribute__((ext_vector_type(4)));

#define MFMA16(a, b, c) __builtin_amdgcn_mfma_f32_16x16x32_bf16((a), (b), (c), 0, 0, 0)

constexpr int NHEADS = 16;

// async global->LDS, 16B per lane; LDS dest = wave-uniform base + lane*16
__device__ __forceinline__ void gld16(const bf16* g, bf16* l) {
  __builtin_amdgcn_global_load_lds(
      (const __attribute__((address_space(1))) void*)g,
      (__attribute__((address_space(3))) void*)l, 16, 0, 0);
}

// ---------------------------------------------------------------------------
// fp32 -> bf16 convert, 8 elems/thread, exact grids (n % 2048 == 0)
// ---------------------------------------------------------------------------
__global__ __launch_bounds__(256) void cvt_bf16(const float* __restrict__ src,
                                                bf16* __restrict__ dst) {
  const int i = blockIdx.x * 256 + threadIdx.x;
  floatx4 a = ((const floatx4*)src)[2 * i];
  floatx4 b = ((const floatx4*)src)[2 * i + 1];
  bf16x8 o = {(bf16)a[0], (bf16)a[1], (bf16)a[2], (bf16)a[3],
              (bf16)b[0], (bf16)b[1], (bf16)b[2], (bf16)b[3]};
  ((bf16x8*)dst)[i] = o;
}

// ---------------------------------------------------------------------------
// GEMM (m97 structure): C[m][n] = sum_k A[m][k]*W[n][k] + bias[n]
// global_load_lds(16B), BK=32, 128x128 tile.
// MODE 0: scatter -> q[B,H,T,64], k[B,H,T,64], vT[B,H,64,T] (bf16)
//         (V path packs 4 consecutive t into one bf16x4 store)
// MODE 1: plain fp32 store outf[m][n]
// ---------------------------------------------------------------------------
template <int MODE>
__global__ __launch_bounds__(256) void gemm_bt(
    const bf16* __restrict__ A, const bf16* __restrict__ W,
    const float* __restrict__ bias, bf16* __restrict__ out0,
    bf16* __restrict__ out1, bf16* __restrict__ out2,
    float* __restrict__ outf) {
  __shared__ __attribute__((aligned(16))) bf16 lds_a[128 * 32];
  __shared__ __attribute__((aligned(16))) bf16 lds_b[128 * 32];

  const int tid = threadIdx.x;
  const int wid = tid >> 6;
  const int lane = tid & 63;
  const int quad = lane >> 4;
  const int l16 = lane & 15;
  const int block_m = blockIdx.y * 128;
  const int block_n = blockIdx.x * 128;
  const int wm = (wid >> 1) * 64;
  const int wn = (wid & 1) * 64;

  floatx4 acc[4][4];
#pragma unroll
  for (int i = 0; i < 4; ++i)
#pragma unroll
    for (int j = 0; j < 4; ++j) acc[i][j] = (floatx4){0.f, 0.f, 0.f, 0.f};

  for (int k0 = 0; k0 < 1024; k0 += 32) {
    // stage A,W tiles: 512 x 16B slots; slot s -> row = s>>2, blk = s&3.
#pragma unroll
    for (int i = 0; i < 2; ++i) {
      const int slot = wid * 128 + i * 64 + lane;
      const int row = slot >> 2;
      const int blk = slot & 3;
      const int lbase = (wid * 128 + i * 64) * 8;  // elems, wave-uniform
      gld16(&A[(size_t)(block_m + row) * 1024 + k0 + blk * 8], &lds_a[lbase]);
      gld16(&W[(size_t)(block_n + row) * 1024 + k0 + blk * 8], &lds_b[lbase]);
    }
    __syncthreads();

    bf16x8 af[4], bf_[4];
#pragma unroll
    for (int mt = 0; mt < 4; ++mt)
      af[mt] = *(const bf16x8*)&lds_a[(wm + mt * 16 + l16) * 32 + quad * 8];
#pragma unroll
    for (int nt = 0; nt < 4; ++nt)
      bf_[nt] = *(const bf16x8*)&lds_b[(wn + nt * 16 + l16) * 32 + quad * 8];
#pragma unroll
    for (int mt = 0; mt < 4; ++mt)
#pragma unroll
      for (int nt = 0; nt < 4; ++nt)
        acc[mt][nt] = MFMA16(af[mt], bf_[nt], acc[mt][nt]);
    __syncthreads();
  }

  // Epilogue. C/D layout (16x16x32): col n = lane&15, row m = quad*4 + reg.
#pragma unroll
  for (int nt = 0; nt < 4; ++nt) {
    const int n = block_n + wn + nt * 16 + l16;
    const float bv = bias[n];
#pragma unroll
    for (int mt = 0; mt < 4; ++mt) {
      const int m0 = block_m + wm + mt * 16 + quad * 4;  // m = m0 + r
      float v4[4];
#pragma unroll
      for (int r = 0; r < 4; ++r) v4[r] = acc[mt][nt][r] + bv;
      if constexpr (MODE == 1) {
#pragma unroll
        for (int r = 0; r < 4; ++r) outf[(size_t)(m0 + r) * 1024 + n] = v4[r];
      } else {
        const int which = n >> 10;  // 0=q 1=k 2=v (block-uniform)
        const int d = n & 1023;
        const int h = d >> 6;
        const int dd = d & 63;
        const int b = m0 >> 11;  // m = b*2048 + t, t0 % 4 == 0
        const int t0 = m0 & 2047;
        const size_t bh = (size_t)(b * NHEADS + h);
        if (which == 0) {
#pragma unroll
          for (int r = 0; r < 4; ++r)
            out0[(bh * 2048 + t0 + r) * 64 + dd] = (bf16)v4[r];
        } else if (which == 1) {
#pragma unroll
          for (int r = 0; r < 4; ++r)
            out1[(bh * 2048 + t0 + r) * 64 + dd] = (bf16)v4[r];
        } else {
          // v transposed: t = t0 + r consecutive -> one 8B store
          bf16x4 pv = {(bf16)v4[0], (bf16)v4[1], (bf16)v4[2], (bf16)v4[3]};
          *(bf16x4*)&out2[(bh * 64 + dd) * 2048 + t0] = pv;
        }
      }
    }
  }
}

// ---------------------------------------------------------------------------
// Flash attention v8: round-1 pipeline (double-buffered K/V, stage(t+1)
// issued at loop top, single __syncthreads per tile -- compiler schedules
// freely; the vmcnt(0) drain at the barrier is ~free since K/V are
// L2-resident) + XCD-swizzled decode (each XCD owns 8 (b,h) pairs = 4MB
// K/V in its L2; FETCH 139->24.6MB) + s_setprio(1) around MFMA bursts
// (T5: multiple independent blocks/CU at different phases to arbitrate).
// Source addrs XOR-pre-swizzled (16B slot c ^= row&7), LDS dest linear,
// same XOR on ds_read_b128 side -> conflict-free fragment reads.
// Fixed-offset exp2, rowsum via MFMA ones-fragment. P round trip in LDS.
// q,k: [B,H,T,64] bf16; vt: [B,H,64,T] bf16; ctx out: [B,T,1024] bf16.
// ---------------------------------------------------------------------------
__global__ __launch_bounds__(256) void flash_attn(
    const bf16* __restrict__ q, const bf16* __restrict__ k,
    const bf16* __restrict__ vt, bf16* __restrict__ ctx) {
  __shared__ __attribute__((aligned(16))) bf16 k_lds[2][64 * 64];
  __shared__ __attribute__((aligned(16))) bf16 v_lds[2][64 * 64];
  __shared__ __attribute__((aligned(16))) bf16 p_lds[4][32][72];

  const int tid = threadIdx.x;
  const int wid = tid >> 6;
  const int lane = tid & 63;
  const int quad = lane >> 4;
  const int l16 = lane & 15;

  // XCD-aware decode: dispatch round-robins wg%8 across XCDs; give each XCD
  // a contiguous chunk of (qtile,h,b) space so one XCD sees all 16 q-tiles
  // of its 8 (b,h) pairs (K/V working set = 8 * 512KB = 4MB = L2/XCD).
  const int wg = blockIdx.x;
  const int nl = (wg & 7) * 128 + (wg >> 3);  // bijective, 1024 % 8 == 0
  const int q0 = (nl & 15) * 128;
  const int h = (nl >> 4) & 15;
  const int b = nl >> 8;
  const size_t bh = (size_t)(b * NHEADS + h);
  const bf16* qb = q + bh * 2048 * 64;
  const bf16* kb = k + bh * 2048 * 64;
  const bf16* vb = vt + bh * 64 * 2048;

  const bf16x8 ones = {(bf16)1.f, (bf16)1.f, (bf16)1.f, (bf16)1.f,
                       (bf16)1.f, (bf16)1.f, (bf16)1.f, (bf16)1.f};

  // ---- staging geometry: wave handles 16 rows of K tile and 16 of V tile.
  // slot s (16B) -> row = s>>3, col16 = s&7; source col pre-swizzled by
  // col16 ^ (row&7); LDS dest linear (wave-uniform base + lane*16).
  const int slot0 = wid * 128 + lane;      // call 0
  const int slot1 = slot0 + 64;            // call 1
  const int row0 = slot0 >> 3, c0 = (slot0 & 7) ^ (row0 & 7);
  const int row1 = slot1 >> 3, c1 = (slot1 & 7) ^ (row1 & 7);
  const bf16* kst0 = kb + (size_t)row0 * 64 + c0 * 8;   // + kt*64 per tile
  const bf16* kst1 = kb + (size_t)row1 * 64 + c1 * 8;
  const bf16* vst0 = vb + (size_t)row0 * 2048 + c0 * 8; // + kt per tile
  const bf16* vst1 = vb + (size_t)row1 * 2048 + c1 * 8;
  const int ldst0 = wid * 1024;            // elems, wave-uniform
  const int ldst1 = wid * 1024 + 512;

  // ---- fragment-read geometry (swizzled): row = X*16 + l16,
  // elem = row*64 + ((slotc ^ (row&7)) * 8), slotc = quad (lo) / quad+4 (hi)
  const int r7 = l16 & 7;
  const int ro = l16 * 64;
  const int sw0 = ro + ((quad ^ r7) * 8);
  const int sw1 = ro + (((quad + 4) ^ r7) * 8);

  bf16x8 qa[2][2];
#pragma unroll
  for (int s = 0; s < 2; ++s) {
    const int row = q0 + wid * 32 + s * 16 + l16;
    qa[s][0] = *(const bf16x8*)&qb[(size_t)row * 64 + quad * 8];
    qa[s][1] = *(const bf16x8*)&qb[(size_t)row * 64 + 32 + quad * 8];
  }

  floatx4 oacc[2][4];
  floatx4 lacc[2];
#pragma unroll
  for (int s = 0; s < 2; ++s) {
    lacc[s] = (floatx4){0.f, 0.f, 0.f, 0.f};
#pragma unroll
    for (int dt = 0; dt < 4; ++dt) oacc[s][dt] = (floatx4){0.f, 0.f, 0.f, 0.f};
  }

  // ---- prologue: stage tile 0 into buffer 0
  gld16(kst0, &k_lds[0][ldst0]);
  gld16(kst1, &k_lds[0][ldst1]);
  gld16(vst0, &v_lds[0][ldst0]);
  gld16(vst1, &v_lds[0][ldst1]);
  __syncthreads();  // drains vmcnt(0) before barrier

  constexpr float L2E = 1.4426950408889634f;
  int cur = 0;
  for (int kt = 0; kt < 2048; kt += 64) {
    // ---- async stage of next tile into the other buffer (overlaps compute)
    if (kt + 64 < 2048) {
      const int nb = cur ^ 1;
      gld16(kst0 + (size_t)(kt + 64) * 64, &k_lds[nb][ldst0]);
      gld16(kst1 + (size_t)(kt + 64) * 64, &k_lds[nb][ldst1]);
      gld16(vst0 + (kt + 64), &v_lds[nb][ldst0]);
      gld16(vst1 + (kt + 64), &v_lds[nb][ldst1]);
    }

    // ---- K and V fragments for this tile (conflict-free swizzled reads)
    const bf16* kbuf = &k_lds[cur][0];
    const bf16* vbuf = &v_lds[cur][0];
    bf16x8 kf0[4], kf1[4], vf0[4], vf1[4];
#pragma unroll
    for (int nt = 0; nt < 4; ++nt) {
      kf0[nt] = *(const bf16x8*)&kbuf[nt * 1024 + sw0];
      kf1[nt] = *(const bf16x8*)&kbuf[nt * 1024 + sw1];
    }
#pragma unroll
    for (int dt = 0; dt < 4; ++dt) {
      vf0[dt] = *(const bf16x8*)&vbuf[dt * 1024 + sw0];
      vf1[dt] = *(const bf16x8*)&vbuf[dt * 1024 + sw1];
    }

    // ---- S = QK^T, P = exp2(S*log2e/8 - 3*log2e) -> LDS (C layout)
#pragma unroll
    for (int s = 0; s < 2; ++s) {
      floatx4 st[4];
      __builtin_amdgcn_s_setprio(1);
#pragma unroll
      for (int nt = 0; nt < 4; ++nt) {
        floatx4 a0 = (floatx4){0.f, 0.f, 0.f, 0.f};
        a0 = MFMA16(qa[s][0], kf0[nt], a0);
        st[nt] = MFMA16(qa[s][1], kf1[nt], a0);
      }
      __builtin_amdgcn_s_setprio(0);
#pragma unroll
      for (int nt = 0; nt < 4; ++nt)
#pragma unroll
        for (int r = 0; r < 4; ++r) {
          const float p =
              __builtin_amdgcn_exp2f(fmaf(st[nt][r], 0.125f * L2E, -3.0f * L2E));
          p_lds[wid][s * 16 + quad * 4 + r][nt * 16 + l16] = (bf16)p;
        }
    }

    // ---- O += P V ; l += P @ 1 (rowsum via matrix pipe)
#pragma unroll
    for (int s = 0; s < 2; ++s) {
      bf16x8 pa0 = *(const bf16x8*)&p_lds[wid][s * 16 + l16][quad * 8];
      bf16x8 pa1 = *(const bf16x8*)&p_lds[wid][s * 16 + l16][32 + quad * 8];
      __builtin_amdgcn_s_setprio(1);
#pragma unroll
      for (int dt = 0; dt < 4; ++dt) {
        oacc[s][dt] = MFMA16(pa0, vf0[dt], oacc[s][dt]);
        oacc[s][dt] = MFMA16(pa1, vf1[dt], oacc[s][dt]);
      }
      lacc[s] = MFMA16(pa0, ones, lacc[s]);
      lacc[s] = MFMA16(pa1, ones, lacc[s]);
      __builtin_amdgcn_s_setprio(0);
    }

    // ---- next-tile stage complete + everyone done reading cur buffer
    __syncthreads();  // compiler drains vmcnt(0) lgkmcnt(0) here
    cur ^= 1;
  }

  // ---- write ctx[b, t, h*64 + d] = O / l  (lacc col-uniform: own lane ok)
#pragma unroll
  for (int s = 0; s < 2; ++s) {
    float linv[4];
#pragma unroll
    for (int r = 0; r < 4; ++r) linv[r] = 1.f / lacc[s][r];
    const size_t base =
        ((size_t)b * 2048 + q0 + wid * 32 + s * 16) * 1024 + h * 64;
#pragma unroll
    for (int dt = 0; dt < 4; ++dt)
#pragma unroll
      for (int r = 0; r < 4; ++r) {
        const float v = oacc[s][dt][r] * linv[r];
        ctx[base + (size_t)(quad * 4 + r) * 1024 + dt * 16 + l16] = (bf16)v;
      }
  }
}

// ---------------------------------------------------------------------------
extern "C" void kernel_launch(void* const* d_in, const int* in_sizes, int n_in,
                              void* d_out, int out_size, void* d_ws,
                              size_t ws_size, hipStream_t stream) {
  const float* x = (const float*)d_in[0];       // [4,2048,1024] fp32
  const float* qkv_w = (const float*)d_in[1];   // [3072,1024]  fp32
  const float* qkv_b = (const float*)d_in[2];   // [3072]       fp32
  const float* out_w = (const float*)d_in[3];   // [1024,1024]  fp32
  const float* out_b = (const float*)d_in[4];   // [1024]       fp32
  float* out = (float*)d_out;                   // [4,2048,1024] fp32

  // xb (16.8MB) lives in d_out's 33.6MB: read only before the final GEMM
  bf16* xb = (bf16*)d_out;

  bf16* ws = (bf16*)d_ws;
  const size_t SZ = (size_t)8192 * 1024;
  bf16* qkvwb = ws;                       // [3072,1024]
  bf16* outwb = qkvwb + 3072 * 1024;      // [1024,1024]
  bf16* qws = outwb + 1024 * 1024;        // [B,H,T,64]
  bf16* kws = qws + SZ;                   // [B,H,T,64]
  bf16* vtws = kws + SZ;                  // [B,H,64,T]
  bf16* ctx = vtws + SZ;                  // [B,T,1024]

  cvt_bf16<<<4096, 256, 0, stream>>>(x, xb);
  cvt_bf16<<<1536, 256, 0, stream>>>(qkv_w, qkvwb);
  cvt_bf16<<<512, 256, 0, stream>>>(out_w, outwb);

  gemm_bt<0><<<dim3(24, 64), 256, 0, stream>>>(xb, qkvwb, qkv_b, qws, kws,
                                               vtws, nullptr);
  flash_attn<<<1024, 256, 0, stream>>>(qws, kws, vtws, ctx);
  gemm_bt<1><<<dim3(8, 64), 256, 0, stream>>>(ctx, outwb, out_b, nullptr,
                                              nullptr, nullptr, out);
}

// Round 5
// 282.076 us; speedup vs baseline: 1.1420x; 1.0654x over previous
//
#include <hip/hip_runtime.h>
#include <hip/hip_bf16.h>

typedef __bf16 bf16;
typedef __bf16 bf16x4 __attribute__((ext_vector_type(4)));
typedef __bf16 bf16x8 __attribute__((ext_vector_type(8)));
typedef float floatx4 __attribute__((ext_vector_type(4)));

#define MFMA16(a, b, c) __builtin_amdgcn_mfma_f32_16x16x32_bf16((a), (b), (c), 0, 0, 0)

constexpr int NHEADS = 16;

// async global->LDS, 16B per lane; LDS dest = wave-uniform base + lane*16
__device__ __forceinline__ void gld16(const bf16* g, bf16* l) {
  __builtin_amdgcn_global_load_lds(
      (const __attribute__((address_space(1))) void*)g,
      (__attribute__((address_space(3))) void*)l, 16, 0, 0);
}

// ---------------------------------------------------------------------------
// fp32 -> bf16 convert, 8 elems/thread, exact grids (n % 2048 == 0)
// ---------------------------------------------------------------------------
__global__ __launch_bounds__(256) void cvt_bf16(const float* __restrict__ src,
                                                bf16* __restrict__ dst) {
  const int i = blockIdx.x * 256 + threadIdx.x;
  floatx4 a = ((const floatx4*)src)[2 * i];
  floatx4 b = ((const floatx4*)src)[2 * i + 1];
  bf16x8 o = {(bf16)a[0], (bf16)a[1], (bf16)a[2], (bf16)a[3],
              (bf16)b[0], (bf16)b[1], (bf16)b[2], (bf16)b[3]};
  ((bf16x8*)dst)[i] = o;
}

// ---------------------------------------------------------------------------
// GEMM (m97 structure): C[m][n] = sum_k A[m][k]*W[n][k] + bias[n]
// global_load_lds(16B), BK=32, 128x128 tile.
// MODE 0: scatter -> q[B,H,T,64], k[B,H,T,64], vT[B,H,64,T] (bf16)
//         (V path packs 4 consecutive t into one bf16x4 store)
// MODE 1: plain fp32 store outf[m][n]
// ---------------------------------------------------------------------------
template <int MODE>
__global__ __launch_bounds__(256) void gemm_bt(
    const bf16* __restrict__ A, const bf16* __restrict__ W,
    const float* __restrict__ bias, bf16* __restrict__ out0,
    bf16* __restrict__ out1, bf16* __restrict__ out2,
    float* __restrict__ outf) {
  __shared__ __attribute__((aligned(16))) bf16 lds_a[128 * 32];
  __shared__ __attribute__((aligned(16))) bf16 lds_b[128 * 32];

  const int tid = threadIdx.x;
  const int wid = tid >> 6;
  const int lane = tid & 63;
  const int quad = lane >> 4;
  const int l16 = lane & 15;
  const int block_m = blockIdx.y * 128;
  const int block_n = blockIdx.x * 128;
  const int wm = (wid >> 1) * 64;
  const int wn = (wid & 1) * 64;

  floatx4 acc[4][4];
#pragma unroll
  for (int i = 0; i < 4; ++i)
#pragma unroll
    for (int j = 0; j < 4; ++j) acc[i][j] = (floatx4){0.f, 0.f, 0.f, 0.f};

  for (int k0 = 0; k0 < 1024; k0 += 32) {
    // stage A,W tiles: 512 x 16B slots; slot s -> row = s>>2, blk = s&3.
#pragma unroll
    for (int i = 0; i < 2; ++i) {
      const int slot = wid * 128 + i * 64 + lane;
      const int row = slot >> 2;
      const int blk = slot & 3;
      const int lbase = (wid * 128 + i * 64) * 8;  // elems, wave-uniform
      gld16(&A[(size_t)(block_m + row) * 1024 + k0 + blk * 8], &lds_a[lbase]);
      gld16(&W[(size_t)(block_n + row) * 1024 + k0 + blk * 8], &lds_b[lbase]);
    }
    __syncthreads();

    bf16x8 af[4], bf_[4];
#pragma unroll
    for (int mt = 0; mt < 4; ++mt)
      af[mt] = *(const bf16x8*)&lds_a[(wm + mt * 16 + l16) * 32 + quad * 8];
#pragma unroll
    for (int nt = 0; nt < 4; ++nt)
      bf_[nt] = *(const bf16x8*)&lds_b[(wn + nt * 16 + l16) * 32 + quad * 8];
#pragma unroll
    for (int mt = 0; mt < 4; ++mt)
#pragma unroll
      for (int nt = 0; nt < 4; ++nt)
        acc[mt][nt] = MFMA16(af[mt], bf_[nt], acc[mt][nt]);
    __syncthreads();
  }

  // Epilogue. C/D layout (16x16x32): col n = lane&15, row m = quad*4 + reg.
#pragma unroll
  for (int nt = 0; nt < 4; ++nt) {
    const int n = block_n + wn + nt * 16 + l16;
    const float bv = bias[n];
#pragma unroll
    for (int mt = 0; mt < 4; ++mt) {
      const int m0 = block_m + wm + mt * 16 + quad * 4;  // m = m0 + r
      float v4[4];
#pragma unroll
      for (int r = 0; r < 4; ++r) v4[r] = acc[mt][nt][r] + bv;
      if constexpr (MODE == 1) {
#pragma unroll
        for (int r = 0; r < 4; ++r) outf[(size_t)(m0 + r) * 1024 + n] = v4[r];
      } else {
        const int which = n >> 10;  // 0=q 1=k 2=v (block-uniform)
        const int d = n & 1023;
        const int h = d >> 6;
        const int dd = d & 63;
        const int b = m0 >> 11;  // m = b*2048 + t, t0 % 4 == 0
        const int t0 = m0 & 2047;
        const size_t bh = (size_t)(b * NHEADS + h);
        if (which == 0) {
#pragma unroll
          for (int r = 0; r < 4; ++r)
            out0[(bh * 2048 + t0 + r) * 64 + dd] = (bf16)v4[r];
        } else if (which == 1) {
#pragma unroll
          for (int r = 0; r < 4; ++r)
            out1[(bh * 2048 + t0 + r) * 64 + dd] = (bf16)v4[r];
        } else {
          // v transposed: t = t0 + r consecutive -> one 8B store
          bf16x4 pv = {(bf16)v4[0], (bf16)v4[1], (bf16)v4[2], (bf16)v4[3]};
          *(bf16x4*)&out2[(bh * 64 + dd) * 2048 + t0] = pv;
        }
      }
    }
  }
}

// ---------------------------------------------------------------------------
// Flash attention v9: grid 512, 4 waves x 64 q-rows (QBLK=64/wave halves
// total waves -> halves redundant K/V fragment LDS reads). XCD-swizzled
// decode (each XCD: 8 heads x 8 q-tiles resident = 4MB K/V in its L2).
// SWAPPED OPERANDS throughout:
//   S^T = mfma(K, Q)   -> lane holds q=l16 col, k=quad*4+r rows
//                         -> P written as packed bf16x4 ds_write_b64
//   O^T = mfma(VT, P), l = mfma(ones, P) -> O cols q=l16, rows d;
//                         rowsum col-indexed -> scalar 1/l per lane;
//                         ctx written as packed bf16x4.
// P stored in K/V-style XOR-swizzled [row][64] buffer (reads = same
// conflict-free sw0/sw1 pattern as K/V; writes 16B-slot swizzled).
// Round-1 sync structure: double-buffered K/V staged by global_load_lds,
// stage(t+1) at loop top, one __syncthreads per tile. No setprio.
// q,k: [B,H,T,64] bf16; vt: [B,H,64,T] bf16; ctx out: [B,T,1024] bf16.
// ---------------------------------------------------------------------------
__global__ __launch_bounds__(256, 2) void flash_attn(
    const bf16* __restrict__ q, const bf16* __restrict__ k,
    const bf16* __restrict__ vt, bf16* __restrict__ ctx) {
  __shared__ __attribute__((aligned(16))) bf16 k_lds[2][64 * 64];
  __shared__ __attribute__((aligned(16))) bf16 v_lds[2][64 * 64];
  __shared__ __attribute__((aligned(16))) bf16 p_lds[4 * 64 * 64];  // per-wid 64 rows

  const int tid = threadIdx.x;
  const int wid = tid >> 6;
  const int lane = tid & 63;
  const int quad = lane >> 4;
  const int l16 = lane & 15;

  // XCD-aware decode: 512 blocks; wg%8 = XCD; each XCD's 64 concurrent
  // blocks span 8 heads x 8 q-tiles -> 8*512KB = 4MB K/V = L2/XCD.
  const int wg = blockIdx.x;
  const int nl = (wg & 7) * 64 + (wg >> 3);  // bijective, 512 % 8 == 0
  const int q0 = (nl & 7) * 256;
  const int h = (nl >> 3) & 15;
  const int b = nl >> 7;
  const size_t bh = (size_t)(b * NHEADS + h);
  const bf16* qb = q + bh * 2048 * 64;
  const bf16* kb = k + bh * 2048 * 64;
  const bf16* vb = vt + bh * 64 * 2048;

  const bf16x8 ones = {(bf16)1.f, (bf16)1.f, (bf16)1.f, (bf16)1.f,
                       (bf16)1.f, (bf16)1.f, (bf16)1.f, (bf16)1.f};

  // ---- staging geometry: 512 x 16B slots across 4 waves (64x64 tile).
  // slot s -> row = s>>3, col16 = s&7; source col pre-swizzled by
  // col16 ^ (row&7); LDS dest linear (wave-uniform base + lane*16).
  const int slot0 = wid * 128 + lane;      // call 0
  const int slot1 = slot0 + 64;            // call 1
  const int row0 = slot0 >> 3, c0 = (slot0 & 7) ^ (row0 & 7);
  const int row1 = slot1 >> 3, c1 = (slot1 & 7) ^ (row1 & 7);
  const bf16* kst0 = kb + (size_t)row0 * 64 + c0 * 8;   // + kt*64 per tile
  const bf16* kst1 = kb + (size_t)row1 * 64 + c1 * 8;
  const bf16* vst0 = vb + (size_t)row0 * 2048 + c0 * 8; // + kt per tile
  const bf16* vst1 = vb + (size_t)row1 * 2048 + c1 * 8;
  const int ldst0 = wid * 1024;            // elems, wave-uniform
  const int ldst1 = wid * 1024 + 512;

  // ---- fragment-read geometry (swizzled): row = X*16 + l16,
  // elem = row*64 + ((slot ^ (row&7)) * 8), slot = quad (lo) / quad+4 (hi)
  const int r7 = l16 & 7;
  const int ro = l16 * 64;
  const int sw0 = ro + ((quad ^ r7) * 8);
  const int sw1 = ro + (((quad + 4) ^ r7) * 8);

  // ---- P write geometry: row = s*16+l16 (+wid*64), logical 16B slot for
  // col nt*16+quad*4 is 2nt+(quad>>1), half = quad&1; swizzle slot^ (l16&7).
  const int pwq = (quad & 1) * 4;  // elems within slot

  bf16x8 qa[4][2];
#pragma unroll
  for (int s = 0; s < 4; ++s) {
    const int row = q0 + wid * 64 + s * 16 + l16;
    qa[s][0] = *(const bf16x8*)&qb[(size_t)row * 64 + quad * 8];
    qa[s][1] = *(const bf16x8*)&qb[(size_t)row * 64 + 32 + quad * 8];
  }

  floatx4 oacc[4][4];
  floatx4 lacc[4];
#pragma unroll
  for (int s = 0; s < 4; ++s) {
    lacc[s] = (floatx4){0.f, 0.f, 0.f, 0.f};
#pragma unroll
    for (int dt = 0; dt < 4; ++dt) oacc[s][dt] = (floatx4){0.f, 0.f, 0.f, 0.f};
  }

  // ---- prologue: stage tile 0 into buffer 0
  gld16(kst0, &k_lds[0][ldst0]);
  gld16(kst1, &k_lds[0][ldst1]);
  gld16(vst0, &v_lds[0][ldst0]);
  gld16(vst1, &v_lds[0][ldst1]);
  __syncthreads();  // drains vmcnt(0) before barrier

  constexpr float L2E = 1.4426950408889634f;
  int cur = 0;
  for (int kt = 0; kt < 2048; kt += 64) {
    // ---- async stage of next tile into the other buffer (overlaps compute)
    if (kt + 64 < 2048) {
      const int nb = cur ^ 1;
      gld16(kst0 + (size_t)(kt + 64) * 64, &k_lds[nb][ldst0]);
      gld16(kst1 + (size_t)(kt + 64) * 64, &k_lds[nb][ldst1]);
      gld16(vst0 + (kt + 64), &v_lds[nb][ldst0]);
      gld16(vst1 + (kt + 64), &v_lds[nb][ldst1]);
    }

    // ---- K and V fragments for this tile (conflict-free swizzled reads)
    const bf16* kbuf = &k_lds[cur][0];
    const bf16* vbuf = &v_lds[cur][0];
    bf16x8 kf0[4], kf1[4], vf0[4], vf1[4];
#pragma unroll
    for (int nt = 0; nt < 4; ++nt) {
      kf0[nt] = *(const bf16x8*)&kbuf[nt * 1024 + sw0];
      kf1[nt] = *(const bf16x8*)&kbuf[nt * 1024 + sw1];
    }
#pragma unroll
    for (int dt = 0; dt < 4; ++dt) {
      vf0[dt] = *(const bf16x8*)&vbuf[dt * 1024 + sw0];
      vf1[dt] = *(const bf16x8*)&vbuf[dt * 1024 + sw1];
    }

#pragma unroll
    for (int s = 0; s < 4; ++s) {
      // ---- S^T = mfma(K, Q): lane holds q = s*16+l16 (col),
      //      k = nt*16 + quad*4 + r (row). P = exp2(S*log2e/8 - 3*log2e).
      floatx4 st[4];
#pragma unroll
      for (int nt = 0; nt < 4; ++nt) {
        floatx4 a0 = (floatx4){0.f, 0.f, 0.f, 0.f};
        a0 = MFMA16(kf0[nt], qa[s][0], a0);
        st[nt] = MFMA16(kf1[nt], qa[s][1], a0);
      }
      // ---- packed P write: 4 consecutive k per lane -> one ds_write_b64
      bf16* prow = &p_lds[(wid * 64 + s * 16 + l16) * 64];
#pragma unroll
      for (int nt = 0; nt < 4; ++nt) {
        float p0 = __builtin_amdgcn_exp2f(fmaf(st[nt][0], 0.125f * L2E, -3.0f * L2E));
        float p1 = __builtin_amdgcn_exp2f(fmaf(st[nt][1], 0.125f * L2E, -3.0f * L2E));
        float p2 = __builtin_amdgcn_exp2f(fmaf(st[nt][2], 0.125f * L2E, -3.0f * L2E));
        float p3 = __builtin_amdgcn_exp2f(fmaf(st[nt][3], 0.125f * L2E, -3.0f * L2E));
        bf16x4 pv = {(bf16)p0, (bf16)p1, (bf16)p2, (bf16)p3};
        const int slot = 2 * nt + (quad >> 1);
        *(bf16x4*)&prow[((slot ^ r7) * 8) + pwq] = pv;
      }

      // ---- P fragments back (same conflict-free pattern as K/V reads)
      const bf16* pbase = &p_lds[(wid * 64 + s * 16) * 64];
      bf16x8 pa0 = *(const bf16x8*)&pbase[sw0];
      bf16x8 pa1 = *(const bf16x8*)&pbase[sw1];

      // ---- O^T += mfma(VT, P): rows d = dt*16+quad*4+r, cols q = l16.
      //      l = mfma(ones, P): col-indexed rowsum (uniform across regs).
#pragma unroll
      for (int dt = 0; dt < 4; ++dt) {
        oacc[s][dt] = MFMA16(vf0[dt], pa0, oacc[s][dt]);
        oacc[s][dt] = MFMA16(vf1[dt], pa1, oacc[s][dt]);
      }
      lacc[s] = MFMA16(ones, pa0, lacc[s]);
      lacc[s] = MFMA16(ones, pa1, lacc[s]);
    }

    // ---- next-tile stage complete + everyone done reading cur buffer
    __syncthreads();  // compiler drains vmcnt(0) lgkmcnt(0) here
    cur ^= 1;
  }

  // ---- write ctx[b, t, h*64 + d] = O / l; q = l16 col -> row fixed per
  // lane, d = dt*16+quad*4+r consecutive -> packed bf16x4 stores.
#pragma unroll
  for (int s = 0; s < 4; ++s) {
    const float linv = 1.f / lacc[s][0];
    const size_t base =
        ((size_t)b * 2048 + q0 + wid * 64 + s * 16 + l16) * 1024 + h * 64;
#pragma unroll
    for (int dt = 0; dt < 4; ++dt) {
      bf16x4 o = {(bf16)(oacc[s][dt][0] * linv), (bf16)(oacc[s][dt][1] * linv),
                  (bf16)(oacc[s][dt][2] * linv), (bf16)(oacc[s][dt][3] * linv)};
      *(bf16x4*)&ctx[base + dt * 16 + quad * 4] = o;
    }
  }
}

// ---------------------------------------------------------------------------
extern "C" void kernel_launch(void* const* d_in, const int* in_sizes, int n_in,
                              void* d_out, int out_size, void* d_ws,
                              size_t ws_size, hipStream_t stream) {
  const float* x = (const float*)d_in[0];       // [4,2048,1024] fp32
  const float* qkv_w = (const float*)d_in[1];   // [3072,1024]  fp32
  const float* qkv_b = (const float*)d_in[2];   // [3072]       fp32
  const float* out_w = (const float*)d_in[3];   // [1024,1024]  fp32
  const float* out_b = (const float*)d_in[4];   // [1024]       fp32
  float* out = (float*)d_out;                   // [4,2048,1024] fp32

  // xb (16.8MB) lives in d_out's 33.6MB: read only before the final GEMM
  bf16* xb = (bf16*)d_out;

  bf16* ws = (bf16*)d_ws;
  const size_t SZ = (size_t)8192 * 1024;
  bf16* qkvwb = ws;                       // [3072,1024]
  bf16* outwb = qkvwb + 3072 * 1024;      // [1024,1024]
  bf16* qws = outwb + 1024 * 1024;        // [B,H,T,64]
  bf16* kws = qws + SZ;                   // [B,H,T,64]
  bf16* vtws = kws + SZ;                  // [B,H,64,T]
  bf16* ctx = vtws + SZ;                  // [B,T,1024]

  cvt_bf16<<<4096, 256, 0, stream>>>(x, xb);
  cvt_bf16<<<1536, 256, 0, stream>>>(qkv_w, qkvwb);
  cvt_bf16<<<512, 256, 0, stream>>>(out_w, outwb);

  gemm_bt<0><<<dim3(24, 64), 256, 0, stream>>>(xb, qkvwb, qkv_b, qws, kws,
                                               vtws, nullptr);
  flash_attn<<<512, 256, 0, stream>>>(qws, kws, vtws, ctx);
  gemm_bt<1><<<dim3(8, 64), 256, 0, stream>>>(ctx, outwb, out_b, nullptr,
                                              nullptr, nullptr, out);
}